// Round 14
// baseline (253.192 us; speedup 1.0000x reference)
//
#include <hip/hip_runtime.h>
#include <hip/hip_bf16.h>
#include <stdint.h>

#define N_TOK 8192
#define D_K   1024
#define NB    128            // block tile (BM=BN=128)
#define BKF   128            // K per MFMA (fp8)
#define NT    (D_K / BKF)    // 8 K-tiles

typedef __attribute__((ext_vector_type(8))) int   i32x8;
typedef __attribute__((ext_vector_type(4))) float f32x4;

__global__ void zero_out_kernel(float* out) { out[0] = 0.0f; }

// fp32 -> OCP e4m3fn, RNE, with subnormal handling (inputs ~N(0,1)).
__device__ __forceinline__ unsigned int f32_to_e4m3(float x) {
  uint32_t u = __builtin_bit_cast(uint32_t, x);
  unsigned int s = (u >> 24) & 0x80u;
  float ax = __builtin_fabsf(x);
  if (ax < 0.015625f) {                    // < 2^-6: subnormal
    int q = (int)rintf(ax * 512.0f);       // 0..8 (8 -> 0x08 = 2^-6 exact)
    return s | (unsigned int)q;
  }
  uint32_t au = u & 0x7FFFFFFFu;
  uint32_t v = au + 0x7FFFFu + ((au >> 20) & 1u);   // RNE at 3 mantissa bits
  int em = (int)(v >> 20) - 960;           // rebias 127->7 (<<3)
  if (em > 0x7E) em = 0x7E;                // clamp to 448 (0x7F = NaN)
  return s | (unsigned int)em;
}

__global__ void __launch_bounds__(256)
convert_kernel(const float* __restrict__ a, const float* __restrict__ b,
               unsigned int* __restrict__ oa, unsigned int* __restrict__ ob) {
  const size_t total4 = (size_t)N_TOK * D_K / 4;
  size_t i = (size_t)blockIdx.x * blockDim.x + threadIdx.x;
  size_t stride = (size_t)gridDim.x * blockDim.x;
  for (; i < total4; i += stride) {
    float4 va = ((const float4*)a)[i];
    float4 vb = ((const float4*)b)[i];
    oa[i] = f32_to_e4m3(va.x) | (f32_to_e4m3(va.y) << 8) |
            (f32_to_e4m3(va.z) << 16) | (f32_to_e4m3(va.w) << 24);
    ob[i] = f32_to_e4m3(vb.x) | (f32_to_e4m3(vb.y) << 8) |
            (f32_to_e4m3(vb.z) << 16) | (f32_to_e4m3(vb.w) << 24);
  }
}

// Fused 128x128-tile MX-fp8 GEMM + sigmoid-contrastive loss, NO LDS path:
// each lane loads its MFMA fragment (32 K-contiguous bytes) directly from
// global as an aligned i32x8 (2x global_load_dwordx4, L1/L2-served).
// Register double-buffer one tile ahead; no barriers in the K-loop.
// R12 post-mortem: LDS staging round-trip (ds_read floor + 4cyc/read
// conflicts) was the ~55us floor; data is K-contiguous in global already.
__global__ void __launch_bounds__(256, 2)
sigc_kernel(const unsigned char* __restrict__ A8,
            const unsigned char* __restrict__ B8,
            const int* __restrict__ labA, const int* __restrict__ labB,
            const float* __restrict__ scale_p, const float* __restrict__ bias_p,
            float* __restrict__ out) {
  __shared__ int sLabA[NB];
  __shared__ int sLabB[NB];
  __shared__ float sPart[4];

  const int tid  = threadIdx.x;
  const int lane = tid & 63;
  const int wid  = tid >> 6;      // 0..3
  const int wr   = wid >> 1;      // 0..1 (M half of 128: rows wr*64..)
  const int wc   = wid & 1;       // 0..1 (N half)
  const int lr   = lane & 15;
  const int kq   = lane >> 4;     // 0..3 (K-quarter: 32B at kq*32)

  // 2-D XCD region mapping on the 64x64 block grid (concurrent panel set
  // per XCD ~2.5 MB < 4 MB L2).
  const int bid = (int)blockIdx.x;
  const int xcd = bid & 7;
  const int ii  = bid >> 3;                    // 0..511
  const int rr  = (xcd >> 1) * 16 + (ii & 15); // 0..63
  const int cc  = (xcd & 1) * 32 + (ii >> 4);  // 0..63
  const int bRow = rr * NB;
  const int bCol = cc * NB;

  if (tid < 128)      sLabA[tid] = labA[bRow + tid];
  else                sLabB[tid - 128] = labB[bCol + (tid - 128)];
  __syncthreads();   // only block-wide sync before the epilogue reads labels

  // Per-lane fragment base pointers (32B-aligned).
  const unsigned char* aBase =
      A8 + (size_t)(bRow + wr * 64 + lr) * D_K + kq * 32;
  const unsigned char* bBase =
      B8 + (size_t)(bCol + wc * 64 + lr) * D_K + kq * 32;

  f32x4 acc[4][4];
#pragma unroll
  for (int i = 0; i < 4; ++i)
#pragma unroll
    for (int j = 0; j < 4; ++j) acc[i][j] = (f32x4){0.f, 0.f, 0.f, 0.f};

  i32x8 fA0[4], fB0[4], fA1[4], fB1[4];

#define LOADT(fa, fb, t) do {                                              \
    _Pragma("unroll") for (int _f = 0; _f < 4; ++_f) {                     \
      fa[_f] = *(const i32x8*)(aBase + (size_t)_f * 16 * D_K + (t) * BKF); \
      fb[_f] = *(const i32x8*)(bBase + (size_t)_f * 16 * D_K + (t) * BKF); \
    } } while (0)

#define MMAT(fa, fb) do {                                                  \
    __builtin_amdgcn_s_setprio(1);                                         \
    _Pragma("unroll") for (int _mf = 0; _mf < 4; ++_mf)                    \
    _Pragma("unroll") for (int _nf = 0; _nf < 4; ++_nf)                    \
      acc[_mf][_nf] = __builtin_amdgcn_mfma_scale_f32_16x16x128_f8f6f4(    \
          fa[_mf], fb[_nf], acc[_mf][_nf], 0, 0,                           \
          0, 0x7F7F7F7F, 0, 0x7F7F7F7F);                                   \
    __builtin_amdgcn_s_setprio(0); } while (0)

  // Prologue: tile 0 fragments.
  LOADT(fA0, fB0, 0);

#pragma unroll
  for (int t2 = 0; t2 < NT / 2; ++t2) {
    const int e = 2 * t2;
    LOADT(fA1, fB1, e + 1);     // issue odd-tile loads under even MFMA
    MMAT(fA0, fB0);
    if (t2 < NT / 2 - 1) LOADT(fA0, fB0, e + 2);
    MMAT(fA1, fB1);
  }

  // Epilogue (exp2-form): per-pair loss = ln2*(max(u,0)+log2(1+2^-|u|)),
  // u = -label*logit*log2e; C/D layout: col=lane&15, row=(lane>>4)*4+r.
  const float L2E = 1.4426950408889634f;
  const float sl2e = scale_p[0] * L2E;
  const float bl2e = bias_p[0] * L2E;
  float loss = 0.0f;
  const int cBase = lane & 15;
  const int rBase = (lane >> 4) * 4;
#pragma unroll
  for (int mf = 0; mf < 4; ++mf)
#pragma unroll
    for (int nf = 0; nf < 4; ++nf) {
      const int colL = sLabB[wc * 64 + nf * 16 + cBase];
#pragma unroll
      for (int r = 0; r < 4; ++r) {
        const int rowL = sLabA[wr * 64 + mf * 16 + rBase + r];
        const float u0 = fmaf(sl2e, acc[mf][nf][r], bl2e);
        const float u = (rowL == colL) ? -u0 : u0;
        loss += fmaxf(u, 0.0f) + log2f(1.0f + exp2f(-fabsf(u)));
      }
    }

#pragma unroll
  for (int off = 32; off > 0; off >>= 1) loss += __shfl_down(loss, off, 64);
  if (lane == 0) sPart[wid] = loss;
  __syncthreads();
  if (tid == 0) {
    const float s = (sPart[0] + sPart[1]) + (sPart[2] + sPart[3]);
    atomicAdd(out, s * (0.6931471805599453f / (float)N_TOK));
  }
}

extern "C" void kernel_launch(void* const* d_in, const int* in_sizes, int n_in,
                              void* d_out, int out_size, void* d_ws, size_t ws_size,
                              hipStream_t stream) {
  const float* a  = (const float*)d_in[0];
  const float* b  = (const float*)d_in[1];
  const int*   la = (const int*)d_in[2];
  const int*   lb = (const int*)d_in[3];
  const float* sc = (const float*)d_in[4];
  const float* bi = (const float*)d_in[5];
  float* out = (float*)d_out;

  unsigned char* wa = (unsigned char*)d_ws;          // fp8 A, 8 MB
  unsigned char* wb = wa + (size_t)N_TOK * D_K;      // fp8 B, 8 MB

  zero_out_kernel<<<1, 1, 0, stream>>>(out);
  convert_kernel<<<2048, 256, 0, stream>>>(a, b, (unsigned int*)wa,
                                           (unsigned int*)wb);
  const int grid = (N_TOK / NB) * (N_TOK / NB);      // 4096
  sigc_kernel<<<grid, 256, 0, stream>>>(wa, wb, la, lb, sc, bi, out);
}

// Round 15
// 125.351 us; speedup vs baseline: 2.0199x; 2.0199x over previous
//
#include <hip/hip_runtime.h>
#include <hip/hip_bf16.h>
#include <stdint.h>

#define N_TOK 8192
#define D_K   1024
#define NB    128            // block tile (BM=BN=128)
#define BKF   128            // K per tile (fp8, one MFMA K-step)
#define NT    8              // K-tiles

typedef __attribute__((ext_vector_type(4))) int   i32x4;
typedef __attribute__((ext_vector_type(8))) int   i32x8;
typedef __attribute__((ext_vector_type(4))) float f32x4;

__global__ void zero_out_kernel(float* out) { out[0] = 0.0f; }

// fp32 -> OCP e4m3fn, RNE, with subnormal handling (inputs ~N(0,1)).
__device__ __forceinline__ unsigned int f32_to_e4m3(float x) {
  uint32_t u = __builtin_bit_cast(uint32_t, x);
  unsigned int s = (u >> 24) & 0x80u;
  float ax = __builtin_fabsf(x);
  if (ax < 0.015625f) {                    // < 2^-6: subnormal
    int q = (int)rintf(ax * 512.0f);       // 0..8 (8 -> 0x08 = 2^-6 exact)
    return s | (unsigned int)q;
  }
  uint32_t au = u & 0x7FFFFFFFu;
  uint32_t v = au + 0x7FFFFu + ((au >> 20) & 1u);   // RNE at 3 mantissa bits
  int em = (int)(v >> 20) - 960;           // rebias 127->7 (<<3)
  if (em > 0x7E) em = 0x7E;                // clamp to 448 (0x7F = NaN)
  return s | (unsigned int)em;
}

__global__ void __launch_bounds__(256)
convert_kernel(const float* __restrict__ a, const float* __restrict__ b,
               unsigned int* __restrict__ oa, unsigned int* __restrict__ ob) {
  const size_t total4 = (size_t)N_TOK * D_K / 4;
  size_t i = (size_t)blockIdx.x * blockDim.x + threadIdx.x;
  size_t stride = (size_t)gridDim.x * blockDim.x;
  for (; i < total4; i += stride) {
    float4 va = ((const float4*)a)[i];
    float4 vb = ((const float4*)b)[i];
    oa[i] = f32_to_e4m3(va.x) | (f32_to_e4m3(va.y) << 8) |
            (f32_to_e4m3(va.z) << 16) | (f32_to_e4m3(va.w) << 24);
    ob[i] = f32_to_e4m3(vb.x) | (f32_to_e4m3(vb.y) << 8) |
            (f32_to_e4m3(vb.z) << 16) | (f32_to_e4m3(vb.w) << 24);
  }
}

// Fused 128x128-tile MX-fp8 GEMM + sigmoid-contrastive loss.
// R14: overlap schedule — frag ds_reads for tile t+1 (alt register set)
// issue right after barrier2, then tile t's 16 MFMAs run; read latency
// hides under the MFMA burst. All LDS addressing is precomputed per-lane
// offsets + compile-time buffer-base immediates (full unroll). Correct
// counted wait restored: 8 staging loads/thread/tile -> vmcnt(8).
__global__ void __launch_bounds__(256, 2)
sigc_kernel(const unsigned char* __restrict__ A8,
            const unsigned char* __restrict__ B8,
            const int* __restrict__ labA, const int* __restrict__ labB,
            const float* __restrict__ scale_p, const float* __restrict__ bias_p,
            float* __restrict__ out) {
  __shared__ unsigned char lds[65536];   // A0|A1|B0|B1, 16 KB each
  __shared__ int sLabA[NB];
  __shared__ int sLabB[NB];
  __shared__ float sPart[4];

#define LA0 0
#define LA1 16384
#define LB0 32768
#define LB1 49152

  const int tid  = threadIdx.x;
  const int lane = tid & 63;
  const int wid  = tid >> 6;      // 0..3
  const int wr   = wid >> 1;      // 0..1
  const int wc   = wid & 1;       // 0..1
  const int lr   = lane & 15;
  const int kq   = lane >> 4;     // 0..3 (K-quarter: 32B at kq*32)

  // 2-D XCD region mapping on the 64x64 block grid.
  const int bid = (int)blockIdx.x;
  const int xcd = bid & 7;
  const int ii  = bid >> 3;                    // 0..511
  const int rr  = (xcd >> 1) * 16 + (ii & 15); // 0..63
  const int cc  = (xcd & 1) * 32 + (ii >> 4);  // 0..63
  const int bRow = rr * NB;
  const int bCol = cc * NB;

  if (tid < 128)      sLabA[tid] = labA[bRow + tid];
  else                sLabB[tid - 128] = labB[bCol + (tid - 128)];

  // Per-lane staging source pointers (T2 swizzle on global source, rule #21).
  const unsigned char* gA[4];
  const unsigned char* gB[4];
#pragma unroll
  for (int ld = 0; ld < 4; ++ld) {
    const int row = ld * 32 + (tid >> 3);
    const int col = ((tid & 7) ^ (row & 7)) << 4;
    gA[ld] = A8 + (size_t)(bRow + row) * D_K + col;
    gB[ld] = B8 + (size_t)(bCol + row) * D_K + col;
  }

  // Per-lane fragment byte-offsets within a 16 KB tile (swizzled).
  int offA[4], offB[4];
#pragma unroll
  for (int f = 0; f < 4; ++f) {
    const int rA = wr * 64 + f * 16 + lr;
    offA[f] = rA * BKF + (((2 * kq) ^ (rA & 7)) << 4);
    const int rB = wc * 64 + f * 16 + lr;
    offB[f] = rB * BKF + (((2 * kq) ^ (rB & 7)) << 4);
  }

#define STAGE(T, AB, BB) do {                                              \
    _Pragma("unroll") for (int _ld = 0; _ld < 4; ++_ld) {                  \
      __builtin_amdgcn_global_load_lds(                                    \
          (const __attribute__((address_space(1))) void*)(gA[_ld] + (T) * BKF), \
          (__attribute__((address_space(3))) void*)(lds + (AB) + _ld * 4096 + wid * 1024), \
          16, 0, 0);                                                       \
      __builtin_amdgcn_global_load_lds(                                    \
          (const __attribute__((address_space(1))) void*)(gB[_ld] + (T) * BKF), \
          (__attribute__((address_space(3))) void*)(lds + (BB) + _ld * 4096 + wid * 1024), \
          16, 0, 0);                                                       \
    } } while (0)

#define RF(AB, BB, FA, FB) do {                                            \
    _Pragma("unroll") for (int _f = 0; _f < 4; ++_f) {                     \
      ((i32x4*)&FA[_f])[0] = *(const i32x4*)&lds[(AB) + offA[_f]];         \
      ((i32x4*)&FA[_f])[1] = *(const i32x4*)&lds[(AB) + (offA[_f] ^ 16)];  \
      ((i32x4*)&FB[_f])[0] = *(const i32x4*)&lds[(BB) + offB[_f]];         \
      ((i32x4*)&FB[_f])[1] = *(const i32x4*)&lds[(BB) + (offB[_f] ^ 16)];  \
    } } while (0)

#define MMAT(FA, FB) do {                                                  \
    __builtin_amdgcn_s_setprio(1);                                         \
    _Pragma("unroll") for (int _mf = 0; _mf < 4; ++_mf)                    \
    _Pragma("unroll") for (int _nf = 0; _nf < 4; ++_nf)                    \
      acc[_mf][_nf] = __builtin_amdgcn_mfma_scale_f32_16x16x128_f8f6f4(    \
          FA[_mf], FB[_nf], acc[_mf][_nf], 0, 0,                           \
          0, 0x7F7F7F7F, 0, 0x7F7F7F7F);                                   \
    __builtin_amdgcn_s_setprio(0); } while (0)

  f32x4 acc[4][4];
#pragma unroll
  for (int i = 0; i < 4; ++i)
#pragma unroll
    for (int j = 0; j < 4; ++j) acc[i][j] = (f32x4){0.f, 0.f, 0.f, 0.f};

  i32x8 fAe[4], fBe[4], fAo[4], fBo[4];

  // Prologue: stage tiles 0,1; retire tile 0 (8 oldest); publish; read frags(0).
  STAGE(0, LA0, LB0);
  STAGE(1, LA1, LB1);
  asm volatile("s_waitcnt vmcnt(8)" ::: "memory");
  __syncthreads();
  RF(LA0, LB0, fAe, fBe);

  // ITER(T): cur frags, next frags, write-buffer bases (parity T&1),
  // read-buffer bases (parity (T+1)&1).
#define ITER(T, FAc, FBc, FAn, FBn, AW, BW, AR, BR) do {                   \
    asm volatile("s_waitcnt lgkmcnt(0)" ::: "memory");                     \
    __builtin_amdgcn_sched_barrier(0);                                     \
    __builtin_amdgcn_s_barrier();            /* buf[T&1] free */           \
    if ((T) <= 5) {                                                        \
      STAGE((T) + 2, AW, BW);                                              \
      asm volatile("s_waitcnt vmcnt(8)" ::: "memory");                     \
    } else if ((T) == 6) {                                                 \
      asm volatile("s_waitcnt vmcnt(0)" ::: "memory");                     \
    }                                                                      \
    __builtin_amdgcn_sched_barrier(0);                                     \
    __builtin_amdgcn_s_barrier();            /* tile T+1 published */      \
    if ((T) <= 6) RF(AR, BR, FAn, FBn);                                    \
    __builtin_amdgcn_sched_barrier(0);                                     \
    MMAT(FAc, FBc);                                                        \
  } while (0)

  ITER(0, fAe, fBe, fAo, fBo, LA0, LB0, LA1, LB1);
  ITER(1, fAo, fBo, fAe, fBe, LA1, LB1, LA0, LB0);
  ITER(2, fAe, fBe, fAo, fBo, LA0, LB0, LA1, LB1);
  ITER(3, fAo, fBo, fAe, fBe, LA1, LB1, LA0, LB0);
  ITER(4, fAe, fBe, fAo, fBo, LA0, LB0, LA1, LB1);
  ITER(5, fAo, fBo, fAe, fBe, LA1, LB1, LA0, LB0);
  ITER(6, fAe, fBe, fAo, fBo, LA0, LB0, LA1, LB1);
  // T=7: last tile, frags already in fAo/fBo.
  asm volatile("s_waitcnt lgkmcnt(0)" ::: "memory");
  __builtin_amdgcn_sched_barrier(0);
  MMAT(fAo, fBo);

  // Epilogue (exp2-form): per-pair loss = ln2*(max(u,0)+log2(1+2^-|u|)),
  // u = -label*logit*log2e; C/D layout: col=lane&15, row=(lane>>4)*4+r.
  const float L2E = 1.4426950408889634f;
  const float sl2e = scale_p[0] * L2E;
  const float bl2e = bias_p[0] * L2E;
  float loss = 0.0f;
  const int cBase = lane & 15;
  const int rBase = (lane >> 4) * 4;
#pragma unroll
  for (int mf = 0; mf < 4; ++mf)
#pragma unroll
    for (int nf = 0; nf < 4; ++nf) {
      const int colL = sLabB[wc * 64 + nf * 16 + cBase];
#pragma unroll
      for (int r = 0; r < 4; ++r) {
        const int rowL = sLabA[wr * 64 + mf * 16 + rBase + r];
        const float u0 = fmaf(sl2e, acc[mf][nf][r], bl2e);
        const float u = (rowL == colL) ? -u0 : u0;
        loss += fmaxf(u, 0.0f) + log2f(1.0f + exp2f(-fabsf(u)));
      }
    }

#pragma unroll
  for (int off = 32; off > 0; off >>= 1) loss += __shfl_down(loss, off, 64);
  if (lane == 0) sPart[wid] = loss;
  __syncthreads();
  if (tid == 0) {
    const float s = (sPart[0] + sPart[1]) + (sPart[2] + sPart[3]);
    atomicAdd(out, s * (0.6931471805599453f / (float)N_TOK));
  }
}

extern "C" void kernel_launch(void* const* d_in, const int* in_sizes, int n_in,
                              void* d_out, int out_size, void* d_ws, size_t ws_size,
                              hipStream_t stream) {
  const float* a  = (const float*)d_in[0];
  const float* b  = (const float*)d_in[1];
  const int*   la = (const int*)d_in[2];
  const int*   lb = (const int*)d_in[3];
  const float* sc = (const float*)d_in[4];
  const float* bi = (const float*)d_in[5];
  float* out = (float*)d_out;

  unsigned char* wa = (unsigned char*)d_ws;          // fp8 A, 8 MB
  unsigned char* wb = wa + (size_t)N_TOK * D_K;      // fp8 B, 8 MB

  zero_out_kernel<<<1, 1, 0, stream>>>(out);
  convert_kernel<<<2048, 256, 0, stream>>>(a, b, (unsigned int*)wa,
                                           (unsigned int*)wb);
  const int grid = (N_TOK / NB) * (N_TOK / NB);      // 4096
  sigc_kernel<<<grid, 256, 0, stream>>>(wa, wb, la, lb, sc, bi, out);
}

// Round 16
// 122.502 us; speedup vs baseline: 2.0668x; 1.0233x over previous
//
#include <hip/hip_runtime.h>
#include <hip/hip_bf16.h>
#include <stdint.h>

#define N_TOK 8192
#define D_K   1024
#define NB    128            // block tile (BM=BN=128)
#define BKF   128            // K per tile (fp8, one MFMA K-step)
#define NT    8              // K-tiles

typedef __attribute__((ext_vector_type(4))) int   i32x4;
typedef __attribute__((ext_vector_type(8))) int   i32x8;
typedef __attribute__((ext_vector_type(4))) float f32x4;

__global__ void zero_out_kernel(float* out) { out[0] = 0.0f; }

// fp32 -> OCP e4m3fn, RNE, with subnormal handling (inputs ~N(0,1)).
__device__ __forceinline__ unsigned int f32_to_e4m3(float x) {
  uint32_t u = __builtin_bit_cast(uint32_t, x);
  unsigned int s = (u >> 24) & 0x80u;
  float ax = __builtin_fabsf(x);
  if (ax < 0.015625f) {                    // < 2^-6: subnormal
    int q = (int)rintf(ax * 512.0f);       // 0..8 (8 -> 0x08 = 2^-6 exact)
    return s | (unsigned int)q;
  }
  uint32_t au = u & 0x7FFFFFFFu;
  uint32_t v = au + 0x7FFFFu + ((au >> 20) & 1u);   // RNE at 3 mantissa bits
  int em = (int)(v >> 20) - 960;           // rebias 127->7 (<<3)
  if (em > 0x7E) em = 0x7E;                // clamp to 448 (0x7F = NaN)
  return s | (unsigned int)em;
}

__global__ void __launch_bounds__(256)
convert_kernel(const float* __restrict__ a, const float* __restrict__ b,
               unsigned int* __restrict__ oa, unsigned int* __restrict__ ob) {
  const size_t total4 = (size_t)N_TOK * D_K / 4;
  size_t i = (size_t)blockIdx.x * blockDim.x + threadIdx.x;
  size_t stride = (size_t)gridDim.x * blockDim.x;
  for (; i < total4; i += stride) {
    float4 va = ((const float4*)a)[i];
    float4 vb = ((const float4*)b)[i];
    oa[i] = f32_to_e4m3(va.x) | (f32_to_e4m3(va.y) << 8) |
            (f32_to_e4m3(va.z) << 16) | (f32_to_e4m3(va.w) << 24);
    ob[i] = f32_to_e4m3(vb.x) | (f32_to_e4m3(vb.y) << 8) |
            (f32_to_e4m3(vb.z) << 16) | (f32_to_e4m3(vb.w) << 24);
  }
}

// Fused 128x128-tile MX-fp8 GEMM + sigmoid-contrastive loss.
// R15: SINGLE-buffered LDS (33 KB -> 3-4 blocks/CU). R14 audit: no pipe
// saturated at 2 blocks/CU — within-wave ds_read->MFMA serialization with
// nothing to overlap. Cross-block TLP (m97's ~3 blocks/CU mechanism) hides
// the per-block stage latency; tile ordering: RF->barrier->STAGE(t+1) into
// same buffer (operands already in regs)->MFMA->vmcnt(0)->barrier.
__global__ void __launch_bounds__(256)
sigc_kernel(const unsigned char* __restrict__ A8,
            const unsigned char* __restrict__ B8,
            const int* __restrict__ labA, const int* __restrict__ labB,
            const float* __restrict__ scale_p, const float* __restrict__ bias_p,
            float* __restrict__ out) {
  __shared__ unsigned char lds[32768];   // A | B, 16 KB each, single buffer
  __shared__ int sLabA[NB];
  __shared__ int sLabB[NB];
  __shared__ float sPart[4];

#define LA 0
#define LB 16384

  const int tid  = threadIdx.x;
  const int lane = tid & 63;
  const int wid  = tid >> 6;      // 0..3
  const int wr   = wid >> 1;      // 0..1
  const int wc   = wid & 1;       // 0..1
  const int lr   = lane & 15;
  const int kq   = lane >> 4;     // 0..3 (K-quarter: 32B at kq*32)

  // 2-D XCD region mapping on the 64x64 block grid.
  const int bid = (int)blockIdx.x;
  const int xcd = bid & 7;
  const int ii  = bid >> 3;                    // 0..511
  const int rr  = (xcd >> 1) * 16 + (ii & 15); // 0..63
  const int cc  = (xcd & 1) * 32 + (ii >> 4);  // 0..63
  const int bRow = rr * NB;
  const int bCol = cc * NB;

  if (tid < 128)      sLabA[tid] = labA[bRow + tid];
  else                sLabB[tid - 128] = labB[bCol + (tid - 128)];

  // Per-lane staging source pointers (T2 swizzle on global source, rule #21).
  const unsigned char* gA[4];
  const unsigned char* gB[4];
#pragma unroll
  for (int ld = 0; ld < 4; ++ld) {
    const int row = ld * 32 + (tid >> 3);
    const int col = ((tid & 7) ^ (row & 7)) << 4;
    gA[ld] = A8 + (size_t)(bRow + row) * D_K + col;
    gB[ld] = B8 + (size_t)(bCol + row) * D_K + col;
  }

  // Per-lane fragment byte-offsets within a 16 KB tile (swizzled).
  int offA[4], offB[4];
#pragma unroll
  for (int f = 0; f < 4; ++f) {
    const int rA = wr * 64 + f * 16 + lr;
    offA[f] = rA * BKF + (((2 * kq) ^ (rA & 7)) << 4);
    const int rB = wc * 64 + f * 16 + lr;
    offB[f] = rB * BKF + (((2 * kq) ^ (rB & 7)) << 4);
  }

#define STAGE(T) do {                                                      \
    _Pragma("unroll") for (int _ld = 0; _ld < 4; ++_ld) {                  \
      __builtin_amdgcn_global_load_lds(                                    \
          (const __attribute__((address_space(1))) void*)(gA[_ld] + (T) * BKF), \
          (__attribute__((address_space(3))) void*)(lds + LA + _ld * 4096 + wid * 1024), \
          16, 0, 0);                                                       \
      __builtin_amdgcn_global_load_lds(                                    \
          (const __attribute__((address_space(1))) void*)(gB[_ld] + (T) * BKF), \
          (__attribute__((address_space(3))) void*)(lds + LB + _ld * 4096 + wid * 1024), \
          16, 0, 0);                                                       \
    } } while (0)

#define RF() do {                                                          \
    _Pragma("unroll") for (int _f = 0; _f < 4; ++_f) {                     \
      ((i32x4*)&fA[_f])[0] = *(const i32x4*)&lds[LA + offA[_f]];           \
      ((i32x4*)&fA[_f])[1] = *(const i32x4*)&lds[LA + (offA[_f] ^ 16)];    \
      ((i32x4*)&fB[_f])[0] = *(const i32x4*)&lds[LB + offB[_f]];           \
      ((i32x4*)&fB[_f])[1] = *(const i32x4*)&lds[LB + (offB[_f] ^ 16)];    \
    } } while (0)

#define MMAT() do {                                                        \
    __builtin_amdgcn_s_setprio(1);                                         \
    _Pragma("unroll") for (int _mf = 0; _mf < 4; ++_mf)                    \
    _Pragma("unroll") for (int _nf = 0; _nf < 4; ++_nf)                    \
      acc[_mf][_nf] = __builtin_amdgcn_mfma_scale_f32_16x16x128_f8f6f4(    \
          fA[_mf], fB[_nf], acc[_mf][_nf], 0, 0,                           \
          0, 0x7F7F7F7F, 0, 0x7F7F7F7F);                                   \
    __builtin_amdgcn_s_setprio(0); } while (0)

  f32x4 acc[4][4];
#pragma unroll
  for (int i = 0; i < 4; ++i)
#pragma unroll
    for (int j = 0; j < 4; ++j) acc[i][j] = (f32x4){0.f, 0.f, 0.f, 0.f};

  i32x8 fA[4], fB[4];

  // Prologue: stage tile 0, drain, publish (also publishes labels).
  STAGE(0);
  asm volatile("s_waitcnt vmcnt(0)" ::: "memory");
  __syncthreads();

#pragma unroll
  for (int t = 0; t < NT; ++t) {
    // Read tile t's fragments into registers.
    RF();
    asm volatile("s_waitcnt lgkmcnt(0)" ::: "memory");
    __builtin_amdgcn_sched_barrier(0);
    __builtin_amdgcn_s_barrier();            // all waves done reading LDS
    if (t < NT - 1) STAGE(t + 1);            // overwrite same buffer
    __builtin_amdgcn_sched_barrier(0);
    MMAT();                                  // covers part of stage latency
    if (t < NT - 1) {
      __builtin_amdgcn_sched_barrier(0);
      asm volatile("s_waitcnt vmcnt(0)" ::: "memory");
      __builtin_amdgcn_s_barrier();          // tile t+1 published
    }
  }

  // Epilogue (exp2-form): per-pair loss = ln2*(max(u,0)+log2(1+2^-|u|)),
  // u = -label*logit*log2e; C/D layout: col=lane&15, row=(lane>>4)*4+r.
  const float L2E = 1.4426950408889634f;
  const float sl2e = scale_p[0] * L2E;
  const float bl2e = bias_p[0] * L2E;
  float loss = 0.0f;
  const int cBase = lane & 15;
  const int rBase = (lane >> 4) * 4;
#pragma unroll
  for (int mf = 0; mf < 4; ++mf)
#pragma unroll
    for (int nf = 0; nf < 4; ++nf) {
      const int colL = sLabB[wc * 64 + nf * 16 + cBase];
#pragma unroll
      for (int r = 0; r < 4; ++r) {
        const int rowL = sLabA[wr * 64 + mf * 16 + rBase + r];
        const float u0 = fmaf(sl2e, acc[mf][nf][r], bl2e);
        const float u = (rowL == colL) ? -u0 : u0;
        loss += fmaxf(u, 0.0f) + log2f(1.0f + exp2f(-fabsf(u)));
      }
    }

#pragma unroll
  for (int off = 32; off > 0; off >>= 1) loss += __shfl_down(loss, off, 64);
  if (lane == 0) sPart[wid] = loss;
  __syncthreads();
  if (tid == 0) {
    const float s = (sPart[0] + sPart[1]) + (sPart[2] + sPart[3]);
    atomicAdd(out, s * (0.6931471805599453f / (float)N_TOK));
  }
}

extern "C" void kernel_launch(void* const* d_in, const int* in_sizes, int n_in,
                              void* d_out, int out_size, void* d_ws, size_t ws_size,
                              hipStream_t stream) {
  const float* a  = (const float*)d_in[0];
  const float* b  = (const float*)d_in[1];
  const int*   la = (const int*)d_in[2];
  const int*   lb = (const int*)d_in[3];
  const float* sc = (const float*)d_in[4];
  const float* bi = (const float*)d_in[5];
  float* out = (float*)d_out;

  unsigned char* wa = (unsigned char*)d_ws;          // fp8 A, 8 MB
  unsigned char* wb = wa + (size_t)N_TOK * D_K;      // fp8 B, 8 MB

  zero_out_kernel<<<1, 1, 0, stream>>>(out);
  convert_kernel<<<2048, 256, 0, stream>>>(a, b, (unsigned int*)wa,
                                           (unsigned int*)wb);
  const int grid = (N_TOK / NB) * (N_TOK / NB);      // 4096
  sigc_kernel<<<grid, 256, 0, stream>>>(wa, wb, la, lb, sc, bi, out);
}